// Round 8
// baseline (2238.248 us; speedup 1.0000x reference)
//
#include <hip/hip_runtime.h>
#include <hip/hip_bf16.h>
#include <cstdint>
#include <cstddef>

#define N_G 50000
#define N_D 20000
#define E_G 300000
#define E_D 150000
#define BATCH 65536

typedef _Float16 f16;
typedef _Float16 f16x8 __attribute__((ext_vector_type(8)));
typedef _Float16 f16x4 __attribute__((ext_vector_type(4)));
typedef float f32x4 __attribute__((ext_vector_type(4)));

__device__ __forceinline__ float clampf(float v) {
    return fminf(fmaxf(v, -60000.f), 60000.f);  // also squashes NaN
}

__device__ __forceinline__ void gl_lds16(const void* g, void* l) {
    __builtin_amdgcn_global_load_lds(
        (const __attribute__((address_space(1))) unsigned int*)g,
        (__attribute__((address_space(3))) unsigned int*)l, 16, 0, 0);
}

// ---------------- GEMM: C[M,N] = act(A[M,K] @ Bt[N,K]^T + bias) ----------------
// 256x128 tile, BK=64, 8 waves (4x2), each wave 64x64 via 4x4x(2 halves) MFMA 16x16x32 f16.
// - global_load_lds width-16 staging; 6 staging loads/wave/K-iter (was 8 at 128-tile)
// - XOR chunk swizzle -> 0 LDS bank conflicts (verified R6)
// - XCD-aware block remap (FETCH 266->66 MB verified R6)
// - optional fused pair-gather (bidx != null); requires M % 256 == 0 on that path
__global__ __launch_bounds__(512) void gemm_f16(
    const f16* __restrict__ A,
    const int* __restrict__ bidx,
    const f16* __restrict__ geneT, const f16* __restrict__ disT, int rowBase,
    const f16* __restrict__ Bt, const float* __restrict__ bias,
    f16* __restrict__ C, int M, int N, int K, int relu, int CB, int RB)
{
    alignas(16) __shared__ f16 sA[256 * 64];
    alignas(16) __shared__ f16 sB[128 * 64];
    const int t = threadIdx.x;
    const int w = t >> 6, l = t & 63;
    const int wm = w >> 1, wn = w & 1;          // 4x2 wave grid
    const int q = l >> 4, lr = l & 15;

    // XCD-aware remap (dispatch round-robins consecutive IDs across 8 XCDs)
    int flat = blockIdx.x;
    int cb, rb;
    if ((RB & 7) == 0) {
        int x = flat & 7, idx = flat >> 3;
        int Sx = RB >> 3;
        cb = idx % CB;
        rb = x * Sx + idx / CB;
    } else {
        cb = flat % CB;
        rb = flat / CB;
    }
    const int mBase = rb * 256, nBase = cb * 128;

    // staging: seg = 8 rows of 128B; lane -> (subrow, 16B chunk)
    const int subrow = l >> 3;   // 0..7
    const int c = l & 7;         // chunk 0..7
    const char* pA[4];
    const char* pD[4];
    const char* pB[2];
    const bool fused = (bidx != nullptr);
#pragma unroll
    for (int j = 0; j < 4; j++) {               // A: 32 segs, wave w owns w*4+j
        int seg = w * 4 + j;
        int lrow = seg * 8 + subrow;            // 0..255
        int coff = ((c ^ (lrow & 7)) << 4);
        if (fused) {
            int rg = rowBase + mBase + lrow;
            int gi = bidx[2 * rg], di = bidx[2 * rg + 1];
            pA[j] = (const char*)geneT + (size_t)gi * 512 + coff;
            pD[j] = (const char*)disT + (size_t)di * 512 + coff;
        } else {
            int arow = mBase + lrow; if (arow > M - 1) arow = M - 1;
            pA[j] = (const char*)A + (size_t)arow * K * 2 + coff;
            pD[j] = nullptr;
        }
    }
#pragma unroll
    for (int j = 0; j < 2; j++) {               // B: 16 segs, wave w owns w*2+j
        int seg = w * 2 + j;
        int lrow = seg * 8 + subrow;            // 0..127
        int coff = ((c ^ (lrow & 7)) << 4);
        int brow = nBase + lrow; if (brow > N - 1) brow = N - 1;
        pB[j] = (const char*)Bt + (size_t)brow * K * 2 + coff;
    }

    f32x4 acc[4][4] = {};

    for (int k0 = 0; k0 < K; k0 += 64) {
        __syncthreads();   // prev iter's LDS reads done
#pragma unroll
        for (int j = 0; j < 4; j++) {
            int seg = w * 4 + j;
            const char* srcA;
            if (fused)
                srcA = (k0 < 256) ? (pA[j] + (size_t)k0 * 2) : (pD[j] + (size_t)(k0 - 256) * 2);
            else
                srcA = pA[j] + (size_t)k0 * 2;
            gl_lds16(srcA, sA + seg * 512);
        }
#pragma unroll
        for (int j = 0; j < 2; j++) {
            int seg = w * 2 + j;
            gl_lds16(pB[j] + (size_t)k0 * 2, sB + seg * 512);
        }
        __syncthreads();   // drain staging
        f16x8 a0[4], a1[4], b0[4], b1[4];
#pragma unroll
        for (int i = 0; i < 4; i++) {
            int r = wm * 64 + i * 16 + lr;      // 0..255
            int rs = r * 64;
            int x0 = (q ^ (r & 7)) << 3;
            int x1 = ((4 + q) ^ (r & 7)) << 3;
            a0[i] = *(const f16x8*)(sA + rs + x0);
            a1[i] = *(const f16x8*)(sA + rs + x1);
        }
#pragma unroll
        for (int jj = 0; jj < 4; jj++) {
            int r = wn * 64 + jj * 16 + lr;     // 0..127
            int rs = r * 64;
            int x0 = (q ^ (r & 7)) << 3;
            int x1 = ((4 + q) ^ (r & 7)) << 3;
            b0[jj] = *(const f16x8*)(sB + rs + x0);
            b1[jj] = *(const f16x8*)(sB + rs + x1);
        }
#pragma unroll
        for (int i = 0; i < 4; i++)
#pragma unroll
            for (int jj = 0; jj < 4; jj++) {
                acc[i][jj] = __builtin_amdgcn_mfma_f32_16x16x32_f16(a0[i], b0[jj], acc[i][jj], 0, 0, 0);
                acc[i][jj] = __builtin_amdgcn_mfma_f32_16x16x32_f16(a1[i], b1[jj], acc[i][jj], 0, 0, 0);
            }
    }

#pragma unroll
    for (int j = 0; j < 4; j++) {
        int col = nBase + wn * 64 + j * 16 + lr;
        float bc = bias ? bias[col] : 0.f;
#pragma unroll
        for (int i = 0; i < 4; i++) {
            int row0 = mBase + wm * 64 + i * 16 + q * 4;
#pragma unroll
            for (int r = 0; r < 4; r++) {
                int row = row0 + r;
                if (row < M) {
                    float v = acc[i][j][r] + bc;
                    if (relu) v = v >= 0.f ? v : 0.01f * v;
                    C[(size_t)row * N + col] = (f16)clampf(v);
                }
            }
        }
    }
}

// ---------------- small kernels ----------------
__global__ void cvt_f32_f16(const float* __restrict__ in, f16* __restrict__ out, size_t n) {
    size_t i = (size_t)blockIdx.x * 256 + threadIdx.x;
    if (i < n) out[i] = (f16)clampf(in[i]);
}

__global__ void count_deg(const int* __restrict__ ei, int E, int* __restrict__ deg) {
    int e = blockIdx.x * 256 + threadIdx.x;
    if (e < E) atomicAdd(&deg[ei[E + e]], 1);
}

__global__ void scan_deg(const int* __restrict__ deg, int* __restrict__ rowptr, int Nn) {
    __shared__ int part[1024];
    const int t = threadIdx.x;
    const int C = (Nn + 1023) >> 10;
    const int base = t * C;
    int s = 0;
    for (int i = 0; i < C; i++) { int idx = base + i; if (idx < Nn) s += deg[idx]; }
    part[t] = s;
    __syncthreads();
    for (int off = 1; off < 1024; off <<= 1) {
        int v = (t >= off) ? part[t - off] : 0;
        __syncthreads();
        part[t] += v;
        __syncthreads();
    }
    int pre = (t == 0) ? 0 : part[t - 1];
    for (int i = 0; i < C; i++) {
        int idx = base + i;
        if (idx < Nn) { rowptr[idx] = pre; pre += deg[idx]; }
    }
    if (t == 1023) rowptr[Nn] = part[1023];
}

__global__ void fill_csr(const int* __restrict__ ei, int E, const int* __restrict__ rowptr,
                         int* __restrict__ cursor, int* __restrict__ csr) {
    int e = blockIdx.x * 256 + threadIdx.x;
    if (e < E) {
        int d = ei[E + e];
        int p = rowptr[d] + atomicAdd(&cursor[d], 1);
        csr[p] = ei[e];
    }
}

// GraphConv via linearity: PS = X @ [Wr|Ws] (gemm), then per node i:
// y[i] = lrelu( sum_{j->i} P[j] + S[i] + br ).  One wave per node; lane l owns cols l*4..l*4+3.
__global__ void agg_lrelu(const int* __restrict__ rowptr, const int* __restrict__ csr,
                          const f16* __restrict__ PS, const float* __restrict__ br,
                          f16* __restrict__ y, int Nn) {
    int gid = blockIdx.x * 256 + threadIdx.x;
    int node = gid >> 6, l = gid & 63;
    if (node >= Nn) return;
    int beg = rowptr[node], end = rowptr[node + 1];
    f16x4 sv = *(const f16x4*)(PS + (size_t)node * 512 + 256 + l * 4);
    float s0 = (float)sv.x + br[l * 4];
    float s1 = (float)sv.y + br[l * 4 + 1];
    float s2 = (float)sv.z + br[l * 4 + 2];
    float s3 = (float)sv.w + br[l * 4 + 3];
    for (int e = beg; e < end; e++) {
        int src = csr[e];
        f16x4 xv = *(const f16x4*)(PS + (size_t)src * 512 + l * 4);
        s0 += (float)xv.x; s1 += (float)xv.y; s2 += (float)xv.z; s3 += (float)xv.w;
    }
    s0 = s0 >= 0.f ? s0 : 0.01f * s0;
    s1 = s1 >= 0.f ? s1 : 0.01f * s1;
    s2 = s2 >= 0.f ? s2 : 0.01f * s2;
    s3 = s3 >= 0.f ? s3 : 0.01f * s3;
    f16x4 o;
    o.x = (f16)clampf(s0); o.y = (f16)clampf(s1);
    o.z = (f16)clampf(s2); o.w = (f16)clampf(s3);
    *(f16x4*)(y + (size_t)node * 256 + l * 4) = o;
}

// WcatT[n][k], n in [0,512), k in [0,256): cols 0..255 = Wr, 256..511 = Ws (B^T layout)
__global__ void build_wcat(const float* __restrict__ Wr, const float* __restrict__ Ws,
                           f16* __restrict__ WcatT) {
    int id = blockIdx.x * 256 + threadIdx.x;  // 512*256
    int n = id >> 8, k = id & 255;
    float v = (n < 256) ? Wr[k * 256 + n] : Ws[k * 256 + (n - 256)];
    WcatT[id] = (f16)clampf(v);
}

// WT[n][k] = W[k][n]   (fp32 -> f16)
__global__ void transpose_w(const float* __restrict__ W, f16* __restrict__ WT, int K, int N) {
    size_t id = (size_t)blockIdx.x * 256 + threadIdx.x;
    if (id >= (size_t)K * N) return;
    int n = (int)(id / K), k = (int)(id % K);
    WT[id] = (f16)clampf(W[(size_t)k * N + n]);
}

__global__ void colstats(const f16* __restrict__ y, int Nrows, float* __restrict__ stats) {
    int col = threadIdx.x;  // 256
    float s = 0, s2 = 0;
    for (int r = blockIdx.x; r < Nrows; r += gridDim.x) {
        float v = (float)y[(size_t)r * 256 + col];
        s += v; s2 += v * v;
    }
    atomicAdd(&stats[col], s);
    atomicAdd(&stats[256 + col], s2);
}

// BN on y; acc (f16, persistent) += w * BN(y)
__global__ void bn_apply(f16* __restrict__ y, const float* __restrict__ stats,
                         const float* __restrict__ g, const float* __restrict__ b,
                         float invN, float w, f16* __restrict__ acc, size_t total) {
    size_t i = (size_t)blockIdx.x * 256 + threadIdx.x;
    if (i >= total) return;
    int col = (int)(i & 255);
    float m = stats[col] * invN;
    float var = stats[256 + col] * invN - m * m;
    if (var < 0.f) var = 0.f;
    float rs = 1.0f / sqrtf(var + 1e-5f);
    float v = ((float)y[i] - m) * rs * g[col] + b[col];
    v = clampf(v);
    y[i] = (f16)v;
    acc[i] = (f16)clampf((float)acc[i] + w * v);
}

// final 512 -> 2 linear, fp32 out; one wave per row
__global__ void lin4_kernel(const f16* __restrict__ h3, const float* __restrict__ W4,
                            const float* __restrict__ b4, float* __restrict__ out,
                            int rows, int rowBase) {
    int gid = blockIdx.x * 256 + threadIdx.x;
    int r = gid >> 6, l = gid & 63;
    if (r >= rows) return;
    const f16* xp = h3 + (size_t)r * 512;
    float s0 = 0, s1 = 0;
    for (int k = l; k < 512; k += 64) {
        float xv = (float)xp[k];
        s0 += xv * W4[k * 2];
        s1 += xv * W4[k * 2 + 1];
    }
    for (int off = 32; off; off >>= 1) {
        s0 += __shfl_down(s0, off);
        s1 += __shfl_down(s1, off);
    }
    if (l == 0) {
        size_t o = (size_t)(rowBase + r) * 2;
        out[o]     = clampf(s0 + b4[0]);
        out[o + 1] = clampf(s1 + b4[1]);
    }
}

extern "C" void kernel_launch(void* const* d_in, const int* in_sizes, int n_in,
                              void* d_out, int out_size, void* d_ws, size_t ws_size,
                              hipStream_t stream) {
    char* ws = (char*)d_ws;
    size_t off = 0;
    auto alloc = [&](size_t bytes) -> void* {
        void* p = ws + off;
        off += (bytes + 255) & ~(size_t)255;
        return p;
    };

    // persistent (~45 MB)
    f16* gene_out = (f16*)alloc((size_t)N_G * 256 * 2);
    f16* dis_out  = (f16*)alloc((size_t)N_D * 256 * 2);
    f16* W1T = (f16*)alloc((size_t)2048 * 512 * 2);
    f16* W2T = (f16*)alloc((size_t)1024 * 2048 * 2);
    f16* W3T = (f16*)alloc((size_t)512 * 1024 * 2);
    f16* WcatT = (f16*)alloc((size_t)512 * 256 * 2);
    int* csr = (int*)alloc((size_t)E_G * 4);
    int* rowptr = (int*)alloc((size_t)(N_G + 1) * 4);
    int* cnt = (int*)alloc((size_t)N_G * 4);
    float* stats = (float*)alloc(512 * 4);

    // scratch: towers use ybA + ybB (25.6 MB each) + PS (51.2 MB); head aliases it
    char* scratch = ws + off;
    size_t avail = (ws_size > off) ? (ws_size - off) : 0;

    f16* ybA = (f16*)scratch;
    f16* ybB = ybA + (size_t)N_G * 256;
    f16* PS  = ybB + (size_t)N_G * 256;   // N_G x 512 f16

    // head chunk: R rows use R*7168 bytes (h1 4KB + h2 2KB + h3 1KB per row)
    int R = BATCH;
    while ((size_t)R * 7168 > avail && R > 256) R >>= 1;
    int chunks = BATCH / R;
    f16* h1 = (f16*)scratch;
    f16* h2 = h1 + (size_t)R * 2048;
    f16* h3 = h2 + (size_t)R * 1024;

    const float* gene_x = (const float*)d_in[0];
    const float* disease_x = (const float*)d_in[1];
    const int* g_ei = (const int*)d_in[2];
    const int* d_ei = (const int*)d_in[3];
    const int* bidx = (const int*)d_in[4];
    float* out = (float*)d_out;

    const float wl[3] = {0.7f, 0.2f, 0.1f};

    auto run_tower = [&](const float* xin, const int* ei, int Nn, int E, int pbase, f16* tout) {
        size_t nelem = (size_t)Nn * 256;
        cvt_f32_f16<<<(int)((nelem + 255) / 256), 256, 0, stream>>>(xin, ybA, nelem);
        hipMemsetAsync(cnt, 0, (size_t)Nn * 4, stream);
        count_deg<<<(E + 255) / 256, 256, 0, stream>>>(ei, E, cnt);
        scan_deg<<<1, 1024, 0, stream>>>(cnt, rowptr, Nn);
        hipMemsetAsync(cnt, 0, (size_t)Nn * 4, stream);
        fill_csr<<<(E + 255) / 256, 256, 0, stream>>>(ei, E, rowptr, cnt, csr);
        hipMemsetAsync(tout, 0, nelem * 2, stream);
        f16* yin = ybA;
        f16* yout = ybB;
        int RB = (Nn + 255) / 256;
        for (int l = 0; l < 3; l++) {
            const float* Wr = (const float*)d_in[pbase + l * 5 + 0];
            const float* br = (const float*)d_in[pbase + l * 5 + 1];
            const float* Wss = (const float*)d_in[pbase + l * 5 + 2];
            const float* bg = (const float*)d_in[pbase + l * 5 + 3];
            const float* bb = (const float*)d_in[pbase + l * 5 + 4];
            build_wcat<<<512, 256, 0, stream>>>(Wr, Wss, WcatT);
            // PS = X @ [Wr|Ws]  (M=Nn, N=512, K=256; no bias, no act)
            gemm_f16<<<4 * RB, 512, 0, stream>>>(yin, nullptr, nullptr, nullptr, 0,
                                                 WcatT, nullptr, PS, Nn, 512, 256, 0, 4, RB);
            agg_lrelu<<<(Nn * 64 + 255) / 256, 256, 0, stream>>>(rowptr, csr, PS, br, yout, Nn);
            hipMemsetAsync(stats, 0, 512 * 4, stream);
            colstats<<<1024, 256, 0, stream>>>(yout, Nn, stats);
            bn_apply<<<(int)((nelem + 255) / 256), 256, 0, stream>>>(
                yout, stats, bg, bb, 1.0f / Nn, wl[l], tout, nelem);
            f16* tmp = yin; yin = yout; yout = tmp;
        }
    };

    run_tower(gene_x, g_ei, N_G, E_G, 5, gene_out);
    run_tower(disease_x, d_ei, N_D, E_D, 20, dis_out);

    const float* lin1_W = (const float*)d_in[35];
    const float* lin1_b = (const float*)d_in[36];
    const float* lin2_W = (const float*)d_in[37];
    const float* lin2_b = (const float*)d_in[38];
    const float* lin3_W = (const float*)d_in[39];
    const float* lin3_b = (const float*)d_in[40];
    const float* lin4_W = (const float*)d_in[41];
    const float* lin4_b = (const float*)d_in[42];

    transpose_w<<<(512 * 2048 + 255) / 256, 256, 0, stream>>>(lin1_W, W1T, 512, 2048);
    transpose_w<<<(2048 * 1024 + 255) / 256, 256, 0, stream>>>(lin2_W, W2T, 2048, 1024);
    transpose_w<<<(1024 * 512 + 255) / 256, 256, 0, stream>>>(lin3_W, W3T, 1024, 512);

    for (int c = 0; c < chunks; c++) {
        int rb = c * R;
        int RB = R / 256;
        // lin1 with fused pair-gather from gene_out/dis_out
        gemm_f16<<<16 * RB, 512, 0, stream>>>(nullptr, bidx, gene_out, dis_out, rb,
                                              W1T, lin1_b, h1, R, 2048, 512, 1, 16, RB);
        gemm_f16<<<8 * RB, 512, 0, stream>>>(h1, nullptr, nullptr, nullptr, 0,
                                             W2T, lin2_b, h2, R, 1024, 2048, 1, 8, RB);
        gemm_f16<<<4 * RB, 512, 0, stream>>>(h2, nullptr, nullptr, nullptr, 0,
                                             W3T, lin3_b, h3, R, 512, 1024, 1, 4, RB);
        lin4_kernel<<<(R * 64) / 256, 256, 0, stream>>>(h3, lin4_W, lin4_b, out, R, rb);
    }
}

// Round 9
// 1921.501 us; speedup vs baseline: 1.1648x; 1.1648x over previous
//
#include <hip/hip_runtime.h>
#include <hip/hip_bf16.h>
#include <cstdint>
#include <cstddef>

#define N_G 50000
#define N_D 20000
#define E_G 300000
#define E_D 150000
#define BATCH 65536

typedef _Float16 f16;
typedef _Float16 f16x8 __attribute__((ext_vector_type(8)));
typedef _Float16 f16x4 __attribute__((ext_vector_type(4)));
typedef float f32x4 __attribute__((ext_vector_type(4)));

__device__ __forceinline__ float clampf(float v) {
    return fminf(fmaxf(v, -60000.f), 60000.f);  // also squashes NaN
}

__device__ __forceinline__ void gl_lds16(const void* g, void* l) {
    __builtin_amdgcn_global_load_lds(
        (const __attribute__((address_space(1))) unsigned int*)g,
        (__attribute__((address_space(3))) unsigned int*)l, 16, 0, 0);
}

// ---------------- GEMM: C[M,N] = act(A[M,K] @ Bt[N,K]^T + bias) ----------------
// R7 structure (known-good): 128x128 tile, BK=64, 4 waves (2x2), 256 threads.
// - global_load_lds width-16 staging
// - XOR chunk swizzle -> 0 LDS bank conflicts (verified R6)
// - XCD-aware block remap (FETCH 266->66 MB verified R6)
// - optional fused pair-gather (bidx != null)
// - optional fused final linear (W4 != null): out[row] += lrelu(C_tile) @ W4 via atomics
__global__ __launch_bounds__(256) void gemm_f16(
    const f16* __restrict__ A,
    const int* __restrict__ bidx,
    const f16* __restrict__ geneT, const f16* __restrict__ disT, int rowBase,
    const f16* __restrict__ Bt, const float* __restrict__ bias,
    f16* __restrict__ C, int M, int N, int K, int relu, int CB, int RB,
    const float* __restrict__ W4, float* __restrict__ outF)
{
    alignas(16) __shared__ f16 sA[128 * 64];
    alignas(16) __shared__ f16 sB[128 * 64];
    const int t = threadIdx.x;
    const int w = t >> 6, l = t & 63;
    const int wm = w >> 1, wn = w & 1;
    const int q = l >> 4, lr = l & 15;

    // XCD-aware remap (dispatch round-robins consecutive IDs across 8 XCDs)
    int flat = blockIdx.x;
    int cb, rb;
    if ((RB & 7) == 0) {
        int x = flat & 7, idx = flat >> 3;
        int Sx = RB >> 3;
        cb = idx % CB;
        rb = x * Sx + idx / CB;
    } else {
        cb = flat % CB;
        rb = flat / CB;
    }
    const int mBase = rb * 128, nBase = cb * 128;

    // staging: load j covers seg=j*4+w, LDS rows [seg*8, seg*8+8); lane -> (subrow, chunk)
    const int subrow = l >> 3;   // 0..7
    const int c = l & 7;         // 16B chunk 0..7 within a 128B row
    const char* pA[4];
    const char* pD[4];
    const char* pB[4];
    const bool fused = (bidx != nullptr);
#pragma unroll
    for (int j = 0; j < 4; j++) {
        int seg = j * 4 + w;
        int lrow = seg * 8 + subrow;               // 0..127
        int coff = ((c ^ (lrow & 7)) << 4);        // swizzled chunk byte offset
        if (fused) {
            int rg = rowBase + mBase + lrow;       // M % 128 == 0 on this path
            int gi = bidx[2 * rg], di = bidx[2 * rg + 1];
            pA[j] = (const char*)geneT + (size_t)gi * 512 + coff;
            pD[j] = (const char*)disT + (size_t)di * 512 + coff;
        } else {
            int arow = mBase + lrow; if (arow > M - 1) arow = M - 1;
            pA[j] = (const char*)A + (size_t)arow * K * 2 + coff;
            pD[j] = nullptr;
        }
        int brow = nBase + lrow; if (brow > N - 1) brow = N - 1;
        pB[j] = (const char*)Bt + (size_t)brow * K * 2 + coff;
    }

    f32x4 acc[4][4] = {};

    for (int k0 = 0; k0 < K; k0 += 64) {
        __syncthreads();   // prev iter's LDS reads done
#pragma unroll
        for (int j = 0; j < 4; j++) {
            int seg = j * 4 + w;
            const char* srcA;
            if (fused)
                srcA = (k0 < 256) ? (pA[j] + (size_t)k0 * 2) : (pD[j] + (size_t)(k0 - 256) * 2);
            else
                srcA = pA[j] + (size_t)k0 * 2;
            gl_lds16(srcA, sA + seg * 512);
            gl_lds16(pB[j] + (size_t)k0 * 2, sB + seg * 512);
        }
        __syncthreads();   // drain staging
        f16x8 a0[4], a1[4], b0[4], b1[4];
#pragma unroll
        for (int i = 0; i < 4; i++) {
            int r = wm * 64 + i * 16 + lr;
            int rs = r * 64;
            int x0 = (q ^ (r & 7)) << 3;
            int x1 = ((4 + q) ^ (r & 7)) << 3;
            a0[i] = *(const f16x8*)(sA + rs + x0);
            a1[i] = *(const f16x8*)(sA + rs + x1);
        }
#pragma unroll
        for (int jj = 0; jj < 4; jj++) {
            int r = wn * 64 + jj * 16 + lr;
            int rs = r * 64;
            int x0 = (q ^ (r & 7)) << 3;
            int x1 = ((4 + q) ^ (r & 7)) << 3;
            b0[jj] = *(const f16x8*)(sB + rs + x0);
            b1[jj] = *(const f16x8*)(sB + rs + x1);
        }
#pragma unroll
        for (int i = 0; i < 4; i++)
#pragma unroll
            for (int jj = 0; jj < 4; jj++) {
                acc[i][jj] = __builtin_amdgcn_mfma_f32_16x16x32_f16(a0[i], b0[jj], acc[i][jj], 0, 0, 0);
                acc[i][jj] = __builtin_amdgcn_mfma_f32_16x16x32_f16(a1[i], b1[jj], acc[i][jj], 0, 0, 0);
            }
    }

    if (W4 != nullptr) {
        // fused final linear: out[rowBase+row] += lrelu(acc + bias) @ W4 (512x2)
        float w40[4], w41[4];
#pragma unroll
        for (int j = 0; j < 4; j++) {
            int col = nBase + wn * 64 + j * 16 + lr;
            w40[j] = W4[col * 2];
            w41[j] = W4[col * 2 + 1];
        }
#pragma unroll
        for (int i = 0; i < 4; i++) {
#pragma unroll
            for (int r = 0; r < 4; r++) {
                int row = mBase + wm * 64 + i * 16 + q * 4 + r;
                float s0 = 0.f, s1 = 0.f;
#pragma unroll
                for (int j = 0; j < 4; j++) {
                    int col = nBase + wn * 64 + j * 16 + lr;
                    float v = acc[i][j][r] + bias[col];
                    v = v >= 0.f ? v : 0.01f * v;
                    v = clampf(v);
                    s0 += v * w40[j];
                    s1 += v * w41[j];
                }
#pragma unroll
                for (int off = 1; off < 16; off <<= 1) {
                    s0 += __shfl_xor(s0, off);
                    s1 += __shfl_xor(s1, off);
                }
                if (lr == 0 && row < M) {
                    atomicAdd(&outF[(size_t)(rowBase + row) * 2], s0);
                    atomicAdd(&outF[(size_t)(rowBase + row) * 2 + 1], s1);
                }
            }
        }
        return;
    }

#pragma unroll
    for (int j = 0; j < 4; j++) {
        int col = nBase + wn * 64 + j * 16 + lr;
        float bc = bias ? bias[col] : 0.f;
#pragma unroll
        for (int i = 0; i < 4; i++) {
            int row0 = mBase + wm * 64 + i * 16 + q * 4;
#pragma unroll
            for (int r = 0; r < 4; r++) {
                int row = row0 + r;
                if (row < M) {
                    float v = acc[i][j][r] + bc;
                    if (relu) v = v >= 0.f ? v : 0.01f * v;
                    C[(size_t)row * N + col] = (f16)clampf(v);
                }
            }
        }
    }
}

// ---------------- small kernels ----------------
__global__ void cvt_f32_f16(const float* __restrict__ in, f16* __restrict__ out, size_t n) {
    size_t i = (size_t)blockIdx.x * 256 + threadIdx.x;
    if (i < n) out[i] = (f16)clampf(in[i]);
}

__global__ void init_out(const float* __restrict__ b4, float* __restrict__ out, int n) {
    int i = blockIdx.x * 256 + threadIdx.x;
    if (i < n) out[i] = b4[i & 1];
}

__global__ void count_deg(const int* __restrict__ ei, int E, int* __restrict__ deg) {
    int e = blockIdx.x * 256 + threadIdx.x;
    if (e < E) atomicAdd(&deg[ei[E + e]], 1);
}

__global__ void scan_deg(const int* __restrict__ deg, int* __restrict__ rowptr, int Nn) {
    __shared__ int part[1024];
    const int t = threadIdx.x;
    const int C = (Nn + 1023) >> 10;
    const int base = t * C;
    int s = 0;
    for (int i = 0; i < C; i++) { int idx = base + i; if (idx < Nn) s += deg[idx]; }
    part[t] = s;
    __syncthreads();
    for (int off = 1; off < 1024; off <<= 1) {
        int v = (t >= off) ? part[t - off] : 0;
        __syncthreads();
        part[t] += v;
        __syncthreads();
    }
    int pre = (t == 0) ? 0 : part[t - 1];
    for (int i = 0; i < C; i++) {
        int idx = base + i;
        if (idx < Nn) { rowptr[idx] = pre; pre += deg[idx]; }
    }
    if (t == 1023) rowptr[Nn] = part[1023];
}

__global__ void fill_csr(const int* __restrict__ ei, int E, const int* __restrict__ rowptr,
                         int* __restrict__ cursor, int* __restrict__ csr) {
    int e = blockIdx.x * 256 + threadIdx.x;
    if (e < E) {
        int d = ei[E + e];
        int p = rowptr[d] + atomicAdd(&cursor[d], 1);
        csr[p] = ei[e];
    }
}

// GraphConv via linearity: PS = X @ [Wr|Ws] (gemm), then per node i:
// y[i] = lrelu( sum_{j->i} P[j] + S[i] + br ).  One wave per node; lane l owns cols l*4..l*4+3.
__global__ void agg_lrelu(const int* __restrict__ rowptr, const int* __restrict__ csr,
                          const f16* __restrict__ PS, const float* __restrict__ br,
                          f16* __restrict__ y, int Nn) {
    int gid = blockIdx.x * 256 + threadIdx.x;
    int node = gid >> 6, l = gid & 63;
    if (node >= Nn) return;
    int beg = rowptr[node], end = rowptr[node + 1];
    f16x4 sv = *(const f16x4*)(PS + (size_t)node * 512 + 256 + l * 4);
    float s0 = (float)sv.x + br[l * 4];
    float s1 = (float)sv.y + br[l * 4 + 1];
    float s2 = (float)sv.z + br[l * 4 + 2];
    float s3 = (float)sv.w + br[l * 4 + 3];
    for (int e = beg; e < end; e++) {
        int src = csr[e];
        f16x4 xv = *(const f16x4*)(PS + (size_t)src * 512 + l * 4);
        s0 += (float)xv.x; s1 += (float)xv.y; s2 += (float)xv.z; s3 += (float)xv.w;
    }
    s0 = s0 >= 0.f ? s0 : 0.01f * s0;
    s1 = s1 >= 0.f ? s1 : 0.01f * s1;
    s2 = s2 >= 0.f ? s2 : 0.01f * s2;
    s3 = s3 >= 0.f ? s3 : 0.01f * s3;
    f16x4 o;
    o.x = (f16)clampf(s0); o.y = (f16)clampf(s1);
    o.z = (f16)clampf(s2); o.w = (f16)clampf(s3);
    *(f16x4*)(y + (size_t)node * 256 + l * 4) = o;
}

// Tiled transpose: WT[dstRowOff + n][k] = W[k][n]; W is K x N fp32, WT rows have length K (f16).
// Coalesced on both sides via 32x33 LDS tile. block (32,8), grid (ceil(N/32), ceil(K/32)).
__global__ void transpose_tile(const float* __restrict__ W, f16* __restrict__ WT,
                               int K, int N, int dstRowOff) {
    __shared__ float tile[32][33];
    int n0 = blockIdx.x * 32, k0 = blockIdx.y * 32;
    int tx = threadIdx.x, ty = threadIdx.y;
    for (int yy = ty; yy < 32; yy += 8) {
        int k = k0 + yy, n = n0 + tx;
        tile[yy][tx] = (k < K && n < N) ? W[(size_t)k * N + n] : 0.f;
    }
    __syncthreads();
    for (int yy = ty; yy < 32; yy += 8) {
        int n = n0 + yy, k = k0 + tx;
        if (n < N && k < K)
            WT[(size_t)(dstRowOff + n) * K + k] = (f16)clampf(tile[tx][yy]);
    }
}

__global__ void colstats(const f16* __restrict__ y, int Nrows, float* __restrict__ stats) {
    int col = threadIdx.x;  // 256
    float s = 0, s2 = 0;
    for (int r = blockIdx.x; r < Nrows; r += gridDim.x) {
        float v = (float)y[(size_t)r * 256 + col];
        s += v; s2 += v * v;
    }
    atomicAdd(&stats[col], s);
    atomicAdd(&stats[256 + col], s2);
}

// BN on y; acc (f16, persistent) += w * BN(y)
__global__ void bn_apply(f16* __restrict__ y, const float* __restrict__ stats,
                         const float* __restrict__ g, const float* __restrict__ b,
                         float invN, float w, f16* __restrict__ acc, size_t total) {
    size_t i = (size_t)blockIdx.x * 256 + threadIdx.x;
    if (i >= total) return;
    int col = (int)(i & 255);
    float m = stats[col] * invN;
    float var = stats[256 + col] * invN - m * m;
    if (var < 0.f) var = 0.f;
    float rs = 1.0f / sqrtf(var + 1e-5f);
    float v = ((float)y[i] - m) * rs * g[col] + b[col];
    v = clampf(v);
    y[i] = (f16)v;
    acc[i] = (f16)clampf((float)acc[i] + w * v);
}

extern "C" void kernel_launch(void* const* d_in, const int* in_sizes, int n_in,
                              void* d_out, int out_size, void* d_ws, size_t ws_size,
                              hipStream_t stream) {
    char* ws = (char*)d_ws;
    size_t off = 0;
    auto alloc = [&](size_t bytes) -> void* {
        void* p = ws + off;
        off += (bytes + 255) & ~(size_t)255;
        return p;
    };

    // persistent (~45 MB)
    f16* gene_out = (f16*)alloc((size_t)N_G * 256 * 2);
    f16* dis_out  = (f16*)alloc((size_t)N_D * 256 * 2);
    f16* W1T = (f16*)alloc((size_t)2048 * 512 * 2);
    f16* W2T = (f16*)alloc((size_t)1024 * 2048 * 2);
    f16* W3T = (f16*)alloc((size_t)512 * 1024 * 2);
    f16* WcatT = (f16*)alloc((size_t)512 * 256 * 2);
    int* csr = (int*)alloc((size_t)E_G * 4);
    int* rowptr = (int*)alloc((size_t)(N_G + 1) * 4);
    int* cnt = (int*)alloc((size_t)N_G * 4);
    float* stats = (float*)alloc(512 * 4);

    // scratch: towers use ybA + ybB (25.6 MB each) + PS (51.2 MB); head aliases it
    char* scratch = ws + off;
    size_t avail = (ws_size > off) ? (ws_size - off) : 0;

    f16* ybA = (f16*)scratch;
    f16* ybB = ybA + (size_t)N_G * 256;
    f16* PS  = ybB + (size_t)N_G * 256;   // N_G x 512 f16

    // head chunk: R rows use R*6144 bytes (h1 4KB + h2 2KB per row; h3 fused away)
    int R = BATCH;
    while ((size_t)R * 6144 > avail && R > 256) R >>= 1;
    int chunks = BATCH / R;
    f16* h1 = (f16*)scratch;
    f16* h2 = h1 + (size_t)R * 2048;

    const float* gene_x = (const float*)d_in[0];
    const float* disease_x = (const float*)d_in[1];
    const int* g_ei = (const int*)d_in[2];
    const int* d_ei = (const int*)d_in[3];
    const int* bidx = (const int*)d_in[4];
    float* out = (float*)d_out;

    const float wl[3] = {0.7f, 0.2f, 0.1f};

    auto run_tower = [&](const float* xin, const int* ei, int Nn, int E, int pbase, f16* tout) {
        size_t nelem = (size_t)Nn * 256;
        cvt_f32_f16<<<(int)((nelem + 255) / 256), 256, 0, stream>>>(xin, ybA, nelem);
        hipMemsetAsync(cnt, 0, (size_t)Nn * 4, stream);
        count_deg<<<(E + 255) / 256, 256, 0, stream>>>(ei, E, cnt);
        scan_deg<<<1, 1024, 0, stream>>>(cnt, rowptr, Nn);
        hipMemsetAsync(cnt, 0, (size_t)Nn * 4, stream);
        fill_csr<<<(E + 255) / 256, 256, 0, stream>>>(ei, E, rowptr, cnt, csr);
        hipMemsetAsync(tout, 0, nelem * 2, stream);
        f16* yin = ybA;
        f16* yout = ybB;
        int RB = (Nn + 127) / 128;
        for (int l = 0; l < 3; l++) {
            const float* Wr = (const float*)d_in[pbase + l * 5 + 0];
            const float* br = (const float*)d_in[pbase + l * 5 + 1];
            const float* Wss = (const float*)d_in[pbase + l * 5 + 2];
            const float* bg = (const float*)d_in[pbase + l * 5 + 3];
            const float* bb = (const float*)d_in[pbase + l * 5 + 4];
            transpose_tile<<<dim3(8, 8), dim3(32, 8), 0, stream>>>(Wr, WcatT, 256, 256, 0);
            transpose_tile<<<dim3(8, 8), dim3(32, 8), 0, stream>>>(Wss, WcatT, 256, 256, 256);
            // PS = X @ [Wr|Ws]  (M=Nn, N=512, K=256; no bias, no act)
            gemm_f16<<<4 * RB, 256, 0, stream>>>(yin, nullptr, nullptr, nullptr, 0,
                                                 WcatT, nullptr, PS, Nn, 512, 256, 0, 4, RB,
                                                 nullptr, nullptr);
            agg_lrelu<<<(Nn * 64 + 255) / 256, 256, 0, stream>>>(rowptr, csr, PS, br, yout, Nn);
            hipMemsetAsync(stats, 0, 512 * 4, stream);
            colstats<<<1024, 256, 0, stream>>>(yout, Nn, stats);
            bn_apply<<<(int)((nelem + 255) / 256), 256, 0, stream>>>(
                yout, stats, bg, bb, 1.0f / Nn, wl[l], tout, nelem);
            f16* tmp = yin; yin = yout; yout = tmp;
        }
    };

    run_tower(gene_x, g_ei, N_G, E_G, 5, gene_out);
    run_tower(disease_x, d_ei, N_D, E_D, 20, dis_out);

    const float* lin1_W = (const float*)d_in[35];
    const float* lin1_b = (const float*)d_in[36];
    const float* lin2_W = (const float*)d_in[37];
    const float* lin2_b = (const float*)d_in[38];
    const float* lin3_W = (const float*)d_in[39];
    const float* lin3_b = (const float*)d_in[40];
    const float* lin4_W = (const float*)d_in[41];
    const float* lin4_b = (const float*)d_in[42];

    transpose_tile<<<dim3(64, 16), dim3(32, 8), 0, stream>>>(lin1_W, W1T, 512, 2048, 0);
    transpose_tile<<<dim3(32, 64), dim3(32, 8), 0, stream>>>(lin2_W, W2T, 2048, 1024, 0);
    transpose_tile<<<dim3(16, 32), dim3(32, 8), 0, stream>>>(lin3_W, W3T, 1024, 512, 0);
    init_out<<<(BATCH * 2 + 255) / 256, 256, 0, stream>>>(lin4_b, out, BATCH * 2);

    for (int c = 0; c < chunks; c++) {
        int rb = c * R;
        int RB = R / 128;
        // lin1 with fused pair-gather from gene_out/dis_out
        gemm_f16<<<16 * RB, 256, 0, stream>>>(nullptr, bidx, gene_out, dis_out, rb,
                                              W1T, lin1_b, h1, R, 2048, 512, 1, 16, RB,
                                              nullptr, nullptr);
        gemm_f16<<<8 * RB, 256, 0, stream>>>(h1, nullptr, nullptr, nullptr, 0,
                                             W2T, lin2_b, h2, R, 1024, 2048, 1, 8, RB,
                                             nullptr, nullptr);
        // lin3 with fused lin4: atomics into out (fp32), rowBase=rb
        gemm_f16<<<4 * RB, 256, 0, stream>>>(h2, nullptr, nullptr, nullptr, rb,
                                             W3T, lin3_b, nullptr, R, 512, 1024, 1, 4, RB,
                                             lin4_W, out);
    }
}